// Round 4
// baseline (229.212 us; speedup 1.0000x reference)
//
#include <hip/hip_runtime.h>

// HMM forward, log-semiring chunked scan, MFMA + 16-ary tree edition.
// B=8, T=4096, S=64.  C=128 chunks of L=32 steps.
// Phase 1 (1024 WGs, 256 thr, 3 WGs/CU): chunk transfer matrix via bf16 MFMA.
//   Depth-2 global_load_lds prefetch, vmcnt never drained inside the loop
//   (raw s_barrier + lgkmcnt only). Emits Et for all chunks, row-major E for
//   chunks % 16 == 0, and row-log m (f32).
// Combine16 (64 WGs, 1 wave): fold 16 chunks/WG with chained MFMA in LDS.
// Final (8 WGs, 1 wave): fold 8 group matrices into alpha -> out[b].

#define HMM_B 8
#define HMM_T 4096
#define HMM_S 64
#define HMM_C 128
#define HMM_L (HMM_T / HMM_C)   // 32

typedef __attribute__((ext_vector_type(8))) short s16x8;
typedef __attribute__((ext_vector_type(4))) float f32x4;
typedef __attribute__((ext_vector_type(4))) unsigned int u32x4;

__device__ inline void gld16(const float* g, const float* l) {
  __builtin_amdgcn_global_load_lds((const __attribute__((address_space(1))) void*)g,
                                   (__attribute__((address_space(3))) void*)l, 16, 0, 0);
}

__device__ inline unsigned cvtpk(float lo, float hi) {
  unsigned r;
  asm("v_cvt_pk_bf16_f32 %0, %1, %2" : "=v"(r) : "v"(lo), "v"(hi));
  return r;
}

__device__ inline float dpp_fmax16(float x) {
  int xi = __float_as_int(x);
  x = fmaxf(x, __int_as_float(__builtin_amdgcn_mov_dpp(xi, 0xB1, 0xF, 0xF, 1)));
  xi = __float_as_int(x);
  x = fmaxf(x, __int_as_float(__builtin_amdgcn_mov_dpp(xi, 0x4E, 0xF, 0xF, 1)));
  xi = __float_as_int(x);
  x = fmaxf(x, __int_as_float(__builtin_amdgcn_mov_dpp(xi, 0x141, 0xF, 0xF, 1)));
  xi = __float_as_int(x);
  x = fmaxf(x, __int_as_float(__builtin_amdgcn_mov_dpp(xi, 0x140, 0xF, 0xF, 1)));
  return x;
}

__device__ inline float bflo(unsigned w) { return __uint_as_float(w << 16); }
__device__ inline float bfhi(unsigned w) { return __uint_as_float(w & 0xffff0000u); }

// ---------------- Phase 1 ----------------

__global__ __launch_bounds__(256, 3)
void hmm_phase1(const float* __restrict__ lf, unsigned short* __restrict__ wsE,
                unsigned short* __restrict__ wsEt, float* __restrict__ wsM) {
  // LDS: 52224 B -> 3 WGs/CU.
  __shared__ struct {
    float fbuf[2][4096];            // f tile; rows are wave-private
    unsigned short fB[4096];        // F bf16, B-frag-linear slots (single buf)
    unsigned short escr[4][1408];   // per-wave E rows, stride 88 ushorts
  } sm;

  const int tid = threadIdx.x;
  const int w   = tid >> 6;     // wave id 0..3 -> output rows 16w..16w+15
  const int l   = tid & 63;     // lane
  const int wg  = blockIdx.x;
  const int bb  = wg >> 7;
  const int cc  = wg & (HMM_C - 1);
  const float* fbase = lf + ((size_t)(bb * HMM_T + cc * HMM_L)) * (HMM_S * HMM_S);

  auto issue = [&](int t) {
    const int par = t & 1;
    const float* fb = fbase + (size_t)t * 4096;
#pragma unroll
    for (int u = 0; u < 4; ++u) {
      int slot = (w * 4 + u) * 64 + l;        // 16B slot index
      int k    = slot >> 4;                   // row of f
      int q16  = slot & 15;                   // swizzled slot-in-row
      const float* src = fb + k * 64 + ((q16 ^ (k & 7)) << 2);
      gld16(src, &sm.fbuf[par][(w * 4 + u) * 256]);
    }
  };

  issue(0);
  issue(1);

  float mracc0 = 0.f, mracc1 = 0.f, mracc2 = 0.f, mracc3 = 0.f;
  const int c4 = l & 15, q = l >> 4;

  for (int t = 0; t < HMM_L; ++t) {
    const int par = t & 1;

    if (t < HMM_L - 1) asm volatile("s_waitcnt vmcnt(4)" ::: "memory");
    else               asm volatile("s_waitcnt vmcnt(0)" ::: "memory");
    __builtin_amdgcn_sched_barrier(0);

    // ---- exp + transpose + pack: my wave's 16 rows -> fB (B-frag-linear)
#pragma unroll
    for (int u = 0; u < 2; ++u) {
      const int g = 2 * w + (l >> 5);         // k-octet index (within my band)
      const int j = (l & 31) + 32 * u;        // column of f
      float v[8];
#pragma unroll
      for (int e = 0; e < 8; ++e) {
        int k = 8 * g + e;
        v[e] = sm.fbuf[par][k * 64 + (((j >> 2) ^ (k & 7)) << 2) + (j & 3)];
      }
      unsigned p0 = cvtpk(__expf(v[0]), __expf(v[1]));
      unsigned p1 = cvtpk(__expf(v[2]), __expf(v[3]));
      unsigned p2 = cvtpk(__expf(v[4]), __expf(v[5]));
      unsigned p3 = cvtpk(__expf(v[6]), __expf(v[7]));
      int slot = ((g >> 2) * 4 + (j >> 4)) * 64 + ((g & 3) << 4) + (j & 15);
      u32x4 o; o.x = p0; o.y = p1; o.z = p2; o.w = p3;
      *(u32x4*)&sm.fB[slot * 8] = o;
    }

    asm volatile("s_waitcnt lgkmcnt(0)" ::: "memory");
    __builtin_amdgcn_sched_barrier(0);
    __builtin_amdgcn_s_barrier();           // barrier1: fB ready, fbuf[par] reads retired
    __builtin_amdgcn_sched_barrier(0);

    if (t + 2 < HMM_L) issue(t + 2);        // refill fbuf[par]; loads stay in flight

    // ---- A fragments (my E rows; identity at t=0)
    s16x8 a0, a1;
    if (t == 0) {
      const int iloc = 16 * w + (l & 15);
      const int kb0 = (l >> 4) * 8, kb1 = 32 + (l >> 4) * 8;
#pragma unroll
      for (int e = 0; e < 8; ++e) {
        a0[e] = (short)((kb0 + e == iloc) ? 0x3F80 : 0);
        a1[e] = (short)((kb1 + e == iloc) ? 0x3F80 : 0);
      }
    } else {
      a0 = *(const s16x8*)&sm.escr[w][(l & 15) * 88 + ((l >> 4) * 8)];
      a1 = *(const s16x8*)&sm.escr[w][(l & 15) * 88 + 32 + ((l >> 4) * 8)];
    }

    // ---- P = E*F : 4 col-tiles x (K=64 as 2 mfma)
    f32x4 acc[4];
#pragma unroll
    for (int n = 0; n < 4; ++n) {
      s16x8 b0 = *(const s16x8*)&sm.fB[((0 + n) * 64 + l) * 8];
      s16x8 b1 = *(const s16x8*)&sm.fB[((4 + n) * 64 + l) * 8];
      f32x4 c = {0.f, 0.f, 0.f, 0.f};
      c = __builtin_amdgcn_mfma_f32_16x16x32_bf16(a0, b0, c, 0, 0, 0);
      c = __builtin_amdgcn_mfma_f32_16x16x32_bf16(a1, b1, c, 0, 0, 0);
      acc[n] = c;
    }

    // ---- epilogue: rowmax, rescale, log-accumulate, store E'
    float inv[4];
    {
      float m0 = fmaxf(fmaxf(acc[0][0], acc[1][0]), fmaxf(acc[2][0], acc[3][0]));
      float m1 = fmaxf(fmaxf(acc[0][1], acc[1][1]), fmaxf(acc[2][1], acc[3][1]));
      float m2 = fmaxf(fmaxf(acc[0][2], acc[1][2]), fmaxf(acc[2][2], acc[3][2]));
      float m3 = fmaxf(fmaxf(acc[0][3], acc[1][3]), fmaxf(acc[2][3], acc[3][3]));
      m0 = dpp_fmax16(m0); m1 = dpp_fmax16(m1);
      m2 = dpp_fmax16(m2); m3 = dpp_fmax16(m3);
      mracc0 += __log2f(m0); mracc1 += __log2f(m1);
      mracc2 += __log2f(m2); mracc3 += __log2f(m3);
      inv[0] = __builtin_amdgcn_rcpf(m0); inv[1] = __builtin_amdgcn_rcpf(m1);
      inv[2] = __builtin_amdgcn_rcpf(m2); inv[3] = __builtin_amdgcn_rcpf(m3);
    }
#pragma unroll
    for (int n = 0; n < 4; ++n) {
      unsigned p0 = cvtpk(acc[n][0] * inv[0], acc[n][1] * inv[1]);
      unsigned p1 = cvtpk(acc[n][2] * inv[2], acc[n][3] * inv[3]);
      sm.escr[w][(4 * q + 0) * 88 + 16 * n + c4] = (unsigned short)(p0 & 0xffffu);
      sm.escr[w][(4 * q + 1) * 88 + 16 * n + c4] = (unsigned short)(p0 >> 16);
      sm.escr[w][(4 * q + 2) * 88 + 16 * n + c4] = (unsigned short)(p1 & 0xffffu);
      sm.escr[w][(4 * q + 3) * 88 + 16 * n + c4] = (unsigned short)(p1 >> 16);
    }

    asm volatile("s_waitcnt lgkmcnt(0)" ::: "memory");
    __builtin_amdgcn_sched_barrier(0);
    __builtin_amdgcn_s_barrier();           // barrier2: fB WAR; vmcnt NOT drained
    __builtin_amdgcn_sched_barrier(0);
  }

  __syncthreads();   // once; escr cross-wave reads below

  // ---- write chunk results
  {
    const size_t cb = ((size_t)(bb * HMM_C + cc)) * 4096;  // ushort elems
    // E^T: wsEt[cb + j*64 + i]
    const int j = tid & 63, p4 = tid >> 6;
    unsigned short o0[8], o1[8];
#pragma unroll
    for (int rl = 0; rl < 8; ++rl)  o0[rl] = sm.escr[p4][rl * 88 + j];
#pragma unroll
    for (int rl = 0; rl < 8; ++rl)  o1[rl] = sm.escr[p4][(rl + 8) * 88 + j];
    *(u32x4*)&wsEt[cb + j * 64 + p4 * 16]     = *(u32x4*)o0;
    *(u32x4*)&wsEt[cb + j * 64 + p4 * 16 + 8] = *(u32x4*)o1;

    // E row-major: only group-leader chunks feed combine16's A operand
    if ((cc & 15) == 0) {
      const int r = tid >> 2, jq = tid & 3;
      u32x4 v0 = *(const u32x4*)&sm.escr[r >> 4][(r & 15) * 88 + jq * 16];
      u32x4 v1 = *(const u32x4*)&sm.escr[r >> 4][(r & 15) * 88 + jq * 16 + 8];
      *(u32x4*)&wsE[cb + r * 64 + jq * 16]     = v0;
      *(u32x4*)&wsE[cb + r * 64 + jq * 16 + 8] = v1;
    }

    if (c4 == 0) {
      const float ln2 = 0.6931471805599453f;
      float* dst = wsM + (size_t)(bb * HMM_C + cc) * 64 + 16 * w + 4 * q;
      dst[0] = mracc0 * ln2; dst[1] = mracc1 * ln2;
      dst[2] = mracc2 * ln2; dst[3] = mracc3 * ln2;
    }
  }
}

// ---------------- 16-ary combine ----------------
// One wave folds chunks [cbase, cbase+16): prod row-normalized bf16, chained
// P = prod . diag(exp(m_c - nu)) . E_c via MFMA; sM[i] tracks log-scale.

__global__ __launch_bounds__(64)
void hmm_combine16(const unsigned short* __restrict__ inE,
                   const unsigned short* __restrict__ inEt,
                   const float* __restrict__ inM,
                   unsigned short* __restrict__ outEt,
                   float* __restrict__ outM) {
  __shared__ float sS[64];
  __shared__ float sM[64];
  __shared__ unsigned short pL[4096];   // prod row-major bf16

  const int l = threadIdx.x, c4 = l & 15, q = l >> 4;
  const int b = blockIdx.x >> 3, g = blockIdx.x & 7;
  const int cbase = b * HMM_C + g * 16;

  // init: prod = E_{cbase}
  s16x8 afr[4][2];
#pragma unroll
  for (int m = 0; m < 4; ++m)
#pragma unroll
    for (int h = 0; h < 2; ++h)
      afr[m][h] = *(const s16x8*)&inE[(size_t)cbase * 4096 +
                                      (m * 16 + c4) * 64 + h * 32 + q * 8];
  sM[l] = inM[(size_t)cbase * 64 + l];

  // prefetch chunk cbase+1
  u32x4 braw[2][4];
  float mv;
  {
    const unsigned short* Et = inEt + (size_t)(cbase + 1) * 4096;
#pragma unroll
    for (int h = 0; h < 2; ++h)
#pragma unroll
      for (int n = 0; n < 4; ++n)
        braw[h][n] = *(const u32x4*)&Et[(n * 16 + c4) * 64 + h * 32 + q * 8];
    mv = inM[(size_t)(cbase + 1) * 64 + l];
  }

  for (int c = 1; c < 16; ++c) {
    u32x4 bcur[2][4];
#pragma unroll
    for (int h = 0; h < 2; ++h)
#pragma unroll
      for (int n = 0; n < 4; ++n) bcur[h][n] = braw[h][n];
    float mcur = mv;
    if (c < 15) {
      const unsigned short* Et = inEt + (size_t)(cbase + c + 1) * 4096;
#pragma unroll
      for (int h = 0; h < 2; ++h)
#pragma unroll
        for (int n = 0; n < 4; ++n)
          braw[h][n] = *(const u32x4*)&Et[(n * 16 + c4) * 64 + h * 32 + q * 8];
      mv = inM[(size_t)(cbase + c + 1) * 64 + l];
    }

    // nu = max(m_c); sS = exp(m_c - nu)
    float nu = mcur;
    nu = fmaxf(nu, __shfl_xor(nu, 1));  nu = fmaxf(nu, __shfl_xor(nu, 2));
    nu = fmaxf(nu, __shfl_xor(nu, 4));  nu = fmaxf(nu, __shfl_xor(nu, 8));
    nu = fmaxf(nu, __shfl_xor(nu, 16)); nu = fmaxf(nu, __shfl_xor(nu, 32));
    sS[l] = __expf(mcur - nu);

    // B fragments: rows of E_c scaled by sS[k]
    s16x8 bfr[2][4];
#pragma unroll
    for (int h = 0; h < 2; ++h) {
      f32x4 s0 = *(const f32x4*)&sS[h * 32 + q * 8];
      f32x4 s1 = *(const f32x4*)&sS[h * 32 + q * 8 + 4];
#pragma unroll
      for (int n = 0; n < 4; ++n) {
        u32x4 raw = bcur[h][n];
        unsigned p0 = cvtpk(bflo(raw.x) * s0[0], bfhi(raw.x) * s0[1]);
        unsigned p1 = cvtpk(bflo(raw.y) * s0[2], bfhi(raw.y) * s0[3]);
        unsigned p2 = cvtpk(bflo(raw.z) * s1[0], bfhi(raw.z) * s1[1]);
        unsigned p3 = cvtpk(bflo(raw.w) * s1[2], bfhi(raw.w) * s1[3]);
        u32x4 o; o.x = p0; o.y = p1; o.z = p2; o.w = p3;
        bfr[h][n] = *(s16x8*)&o;
      }
    }

    f32x4 acc[4][4];
#pragma unroll
    for (int m = 0; m < 4; ++m)
#pragma unroll
      for (int n = 0; n < 4; ++n) {
        f32x4 cc2 = {0.f, 0.f, 0.f, 0.f};
        cc2 = __builtin_amdgcn_mfma_f32_16x16x32_bf16(afr[m][0], bfr[0][n], cc2, 0, 0, 0);
        cc2 = __builtin_amdgcn_mfma_f32_16x16x32_bf16(afr[m][1], bfr[1][n], cc2, 0, 0, 0);
        acc[m][n] = cc2;
      }

    // rowmax per (m, r) over n and the 16-lane col group
    float rmax[4][4];
#pragma unroll
    for (int m = 0; m < 4; ++m)
#pragma unroll
      for (int r = 0; r < 4; ++r) {
        float v = fmaxf(fmaxf(acc[m][0][r], acc[m][1][r]),
                        fmaxf(acc[m][2][r], acc[m][3][r]));
        v = fmaxf(v, __shfl_xor(v, 1));
        v = fmaxf(v, __shfl_xor(v, 2));
        v = fmaxf(v, __shfl_xor(v, 4));
        v = fmaxf(v, __shfl_xor(v, 8));
        rmax[m][r] = v;
      }
    if (c4 == 0) {
#pragma unroll
      for (int m = 0; m < 4; ++m)
#pragma unroll
        for (int r = 0; r < 4; ++r)
          sM[16 * m + 4 * q + r] += nu + __logf(rmax[m][r]);
    }

    if (c < 15) {
      // normalize -> pL row-major, reread A fragments
#pragma unroll
      for (int m = 0; m < 4; ++m) {
        float i0 = __builtin_amdgcn_rcpf(rmax[m][0]);
        float i1 = __builtin_amdgcn_rcpf(rmax[m][1]);
        float i2 = __builtin_amdgcn_rcpf(rmax[m][2]);
        float i3 = __builtin_amdgcn_rcpf(rmax[m][3]);
#pragma unroll
        for (int n = 0; n < 4; ++n) {
          unsigned p01 = cvtpk(acc[m][n][0] * i0, acc[m][n][1] * i1);
          unsigned p23 = cvtpk(acc[m][n][2] * i2, acc[m][n][3] * i3);
          pL[(16 * m + 4 * q + 0) * 64 + 16 * n + c4] = (unsigned short)(p01 & 0xffffu);
          pL[(16 * m + 4 * q + 1) * 64 + 16 * n + c4] = (unsigned short)(p01 >> 16);
          pL[(16 * m + 4 * q + 2) * 64 + 16 * n + c4] = (unsigned short)(p23 & 0xffffu);
          pL[(16 * m + 4 * q + 3) * 64 + 16 * n + c4] = (unsigned short)(p23 >> 16);
        }
      }
#pragma unroll
      for (int m = 0; m < 4; ++m)
#pragma unroll
        for (int h = 0; h < 2; ++h)
          afr[m][h] = *(const s16x8*)&pL[(m * 16 + c4) * 64 + h * 32 + q * 8];
    } else {
      // final: packed E^T store + M store
      const size_t oi = (size_t)(b * 8 + g) * 4096;
#pragma unroll
      for (int m = 0; m < 4; ++m) {
        float i0 = __builtin_amdgcn_rcpf(rmax[m][0]);
        float i1 = __builtin_amdgcn_rcpf(rmax[m][1]);
        float i2 = __builtin_amdgcn_rcpf(rmax[m][2]);
        float i3 = __builtin_amdgcn_rcpf(rmax[m][3]);
#pragma unroll
        for (int n = 0; n < 4; ++n) {
          unsigned p01 = cvtpk(acc[m][n][0] * i0, acc[m][n][1] * i1);
          unsigned p23 = cvtpk(acc[m][n][2] * i2, acc[m][n][3] * i3);
          unsigned long long packed = (unsigned long long)p01 |
                                      ((unsigned long long)p23 << 32);
          *(unsigned long long*)&outEt[oi + (16 * n + c4) * 64 + 16 * m + 4 * q] = packed;
        }
      }
      outM[(size_t)(b * 8 + g) * 64 + l] = sM[l];
    }
  }
}

// ---------------- Final ----------------

__device__ inline float rdlane(float v, int t) {
  return __int_as_float(__builtin_amdgcn_readlane(__float_as_int(v), t));
}

__global__ __launch_bounds__(64)
void hmm_final(const unsigned short* __restrict__ Et, const float* __restrict__ M,
               const float* __restrict__ linit, float* __restrict__ out) {
  const int b = blockIdx.x, l = threadIdx.x;
  float alpha = linit[b * 64 + l];

  int4 e[8]; float mg;
  {
    const int4* src = (const int4*)(Et + (size_t)(b * 8) * 4096 + (size_t)l * 64);
#pragma unroll
    for (int u = 0; u < 8; ++u) e[u] = src[u];
    mg = M[(size_t)(b * 8) * 64 + l];
  }

  for (int g = 0; g < 8; ++g) {
    int4 ec[8];
#pragma unroll
    for (int u = 0; u < 8; ++u) ec[u] = e[u];
    float mcur = mg;
    if (g < 7) {
      const int4* src = (const int4*)(Et + (size_t)(b * 8 + g + 1) * 4096 + (size_t)l * 64);
#pragma unroll
      for (int u = 0; u < 8; ++u) e[u] = src[u];
      mg = M[(size_t)(b * 8 + g + 1) * 64 + l];
    }

    float av = alpha + mcur;
    float mx = av;
    mx = fmaxf(mx, __shfl_xor(mx, 1));  mx = fmaxf(mx, __shfl_xor(mx, 2));
    mx = fmaxf(mx, __shfl_xor(mx, 4));  mx = fmaxf(mx, __shfl_xor(mx, 8));
    mx = fmaxf(mx, __shfl_xor(mx, 16)); mx = fmaxf(mx, __shfl_xor(mx, 32));
    float wv = __expf(av - mx);
    float s = 0.f;
#pragma unroll
    for (int u = 0; u < 8; ++u) {
      unsigned w0 = (unsigned)ec[u].x, w1 = (unsigned)ec[u].y;
      unsigned w2 = (unsigned)ec[u].z, w3 = (unsigned)ec[u].w;
      s = fmaf(rdlane(wv, 8 * u + 0), bflo(w0), s);
      s = fmaf(rdlane(wv, 8 * u + 1), bfhi(w0), s);
      s = fmaf(rdlane(wv, 8 * u + 2), bflo(w1), s);
      s = fmaf(rdlane(wv, 8 * u + 3), bfhi(w1), s);
      s = fmaf(rdlane(wv, 8 * u + 4), bflo(w2), s);
      s = fmaf(rdlane(wv, 8 * u + 5), bfhi(w2), s);
      s = fmaf(rdlane(wv, 8 * u + 6), bflo(w3), s);
      s = fmaf(rdlane(wv, 8 * u + 7), bfhi(w3), s);
    }
    alpha = mx + __logf(s);
  }

  float mx = alpha;
  mx = fmaxf(mx, __shfl_xor(mx, 1));  mx = fmaxf(mx, __shfl_xor(mx, 2));
  mx = fmaxf(mx, __shfl_xor(mx, 4));  mx = fmaxf(mx, __shfl_xor(mx, 8));
  mx = fmaxf(mx, __shfl_xor(mx, 16)); mx = fmaxf(mx, __shfl_xor(mx, 32));
  float s = __expf(alpha - mx);
  s += __shfl_xor(s, 1);  s += __shfl_xor(s, 2);  s += __shfl_xor(s, 4);
  s += __shfl_xor(s, 8);  s += __shfl_xor(s, 16); s += __shfl_xor(s, 32);
  if (l == 0) out[b] = mx + __logf(s);
}

extern "C" void kernel_launch(void* const* d_in, const int* in_sizes, int n_in,
                              void* d_out, int out_size, void* d_ws, size_t ws_size,
                              hipStream_t stream) {
  (void)in_sizes; (void)n_in; (void)out_size; (void)ws_size;
  const float* lf    = (const float*)d_in[0];  // [B,T,S,S] fp32
  const float* linit = (const float*)d_in[1];  // [B,S] fp32
  float* out = (float*)d_out;                  // [B] fp32

  unsigned short* E_A  = (unsigned short*)d_ws;                 // 8 MB (sparse)
  unsigned short* Et_A = E_A + (size_t)1024 * 4096;             // 8 MB
  float*          M_A  = (float*)(Et_A + (size_t)1024 * 4096);  // 256 KB
  unsigned short* Et_B = (unsigned short*)(M_A + (size_t)1024 * 64);  // 512 KB
  float*          M_B  = (float*)(Et_B + (size_t)64 * 4096);    // 16 KB

  hmm_phase1<<<dim3(HMM_B * HMM_C), dim3(256), 0, stream>>>(lf, E_A, Et_A, M_A);
  hmm_combine16<<<dim3(64), dim3(64), 0, stream>>>(E_A, Et_A, M_A, Et_B, M_B);
  hmm_final<<<dim3(HMM_B), dim3(64), 0, stream>>>(Et_B, M_B, linit, out);
}